// Round 1
// 1246.861 us; speedup vs baseline: 1.5286x; 1.5286x over previous
//
#include <hip/hip_runtime.h>
#include <cstdint>
#include <cstddef>

// B=8, S=2048, D=H=1024, fp32 in/out.
// Pipeline (all GEMMs on bf16 MFMA 16x16x32, fp32 accumulate):
//   split(x_batch), split(lin_w), splitT(W_q), splitT(W_k), splitT_h(W_v)
//   x   = xb @ lin_w^T + b      [SPLIT 3-pass, out: bf16 hi/lo -> F region]
//   Q,K = x @ W                 [SPLIT, out: hi/lo pairs (+K fp32 cache)]
//   V   = x_h @ W_v_h           [single pass, fp32 cache]
//   S_b = Q_b K_b^T (causal)    [SPLIT, fp32, ALL batches one dispatch, packed]
//   P_b = softmax(S_b) -> bf16  [ALL batches one dispatch, packed]
//   V^T transpose               [batched, into dead K-pair region]
//   F_b = P_b @ V_b             [ALL batches one dispatch, packed-A]
//
// Causal-packed S: per batch only the 136 lower-triangle 128x128 blocks
// (8.9 MB fp32). Hybrid storage: batches 0-6 in F region (dead between x-pair
// staging and PV write), batch 7 in ws weights region (dead after V GEMM).
// P packed bf16 (35.7 MB) overwrites dead Q pair; VhT overwrites dead K pair.
// ws need: Qpair(64MiB)+Kpair(64MiB)+weights(14MiB) = 148.9 MB (< proven 201.3).

typedef short bf16x8 __attribute__((ext_vector_type(8)));
typedef float f32x4 __attribute__((ext_vector_type(4)));

__device__ __forceinline__ unsigned short f2bf(float f) {
    unsigned u = __float_as_uint(f);
    return (unsigned short)((u + 0x7fffu + ((u >> 16) & 1u)) >> 16);
}
__device__ __forceinline__ float bf2f(unsigned short h) {
    return __uint_as_float(((unsigned)h) << 16);
}

#define GLDS(gp, lp)                                                                \
    __builtin_amdgcn_global_load_lds((const __attribute__((address_space(1))) void*)(gp), \
                                     (__attribute__((address_space(3))) void*)(lp), 16, 0, 0)

// packed-S constants: 136 blocks/batch, 16384 elems/block
#define PACK_BATCH ((size_t)136 * 16384)

// ---------------- conversion kernels ----------------

__global__ __launch_bounds__(256)
void cvt_split(const float* __restrict__ in, unsigned short* __restrict__ h,
               unsigned short* __restrict__ l, size_t n4)
{
    size_t i = (size_t)blockIdx.x * blockDim.x + threadIdx.x;
    size_t stride = (size_t)gridDim.x * blockDim.x;
    for (; i < n4; i += stride) {
        float4 v = ((const float4*)in)[i];
        unsigned short h0 = f2bf(v.x), h1 = f2bf(v.y), h2 = f2bf(v.z), h3 = f2bf(v.w);
        uint2 hp, lp;
        hp.x = (unsigned)h0 | ((unsigned)h1 << 16);
        hp.y = (unsigned)h2 | ((unsigned)h3 << 16);
        lp.x = (unsigned)f2bf(v.x - bf2f(h0)) | ((unsigned)f2bf(v.y - bf2f(h1)) << 16);
        lp.y = (unsigned)f2bf(v.z - bf2f(h2)) | ((unsigned)f2bf(v.w - bf2f(h3)) << 16);
        ((uint2*)h)[i] = hp;
        ((uint2*)l)[i] = lp;
    }
}

// out[c][r] = in[r][c], fp32 -> bf16 hi (+lo). Coalesced both sides via LDS tile.
template<bool PAIR>
__global__ __launch_bounds__(256)
void cvt_split_T(const float* __restrict__ in, unsigned short* __restrict__ hT,
                 unsigned short* __restrict__ lT, int R, int C,
                 size_t inBatch, size_t outBatch)
{
    __shared__ float tile[64][65];
    in += (size_t)blockIdx.z * inBatch;
    hT += (size_t)blockIdx.z * outBatch;
    const int c0 = blockIdx.x * 64, r0 = blockIdx.y * 64;
    const int tx = threadIdx.x & 63, ty = threadIdx.x >> 6;
    for (int i = ty; i < 64; i += 4)
        tile[i][tx] = in[(size_t)(r0 + i) * C + c0 + tx];
    __syncthreads();
    for (int i = ty; i < 64; i += 4) {
        float v = tile[tx][i];
        unsigned short hh = f2bf(v);
        size_t off = (size_t)(c0 + i) * R + r0 + tx;
        hT[off] = hh;
        if (PAIR) (lT + (size_t)blockIdx.z * outBatch)[off] = f2bf(v - bf2f(hh));
    }
}

// ---------------- MFMA GEMM, BT layout everywhere ----------------
// C[M,N] = (Ah+Al)[M,K] @ (Bh+Bl)[N,K]^T.  128x128 block, BK=32, 4 waves (2x2 of 64x64).
// LDS is fragment-contiguous: chunk c (1 KB) holds rows [16c,16c+16) x 32k in MFMA
// lane order, so global_load_lds (base + lane*16) writes it directly and
// ds_read_b128 at (chunk, lane*16) is conflict-free.
// PACKC: write C into causal-packed triangular layout (QK^T, batched over z).
// PACKA: read A from causal-packed layout (PV, batched over z).
// Hybrid packed base: batches 0-6 at C, batch 7 at C7 (different memory region).

template<bool SPLIT, bool BIAS, bool CMASK, bool CK, bool OUTF, bool OUTH, bool OUTL,
         bool PACKC, bool PACKA>
__global__ __launch_bounds__(256)
void gemm_bf16(const unsigned short* __restrict__ Ah, const unsigned short* __restrict__ Al,
               const unsigned short* __restrict__ Bh, const unsigned short* __restrict__ Bl,
               const float* __restrict__ bias,
               float* __restrict__ C, float* __restrict__ C7,
               unsigned short* __restrict__ Ch, unsigned short* __restrict__ Cl,
               int K, int ldA, int ldB, int ldC,
               size_t aBatch, size_t bBatch, size_t cBatch)
{
    const int row0 = blockIdx.y * 128, col0 = blockIdx.x * 128;
    if (CMASK && col0 > row0 + 127) return;

    const int bz = blockIdx.z;
    if (aBatch) { Ah += (size_t)bz * aBatch; if (SPLIT) Al += (size_t)bz * aBatch; }
    if (bBatch) { Bh += (size_t)bz * bBatch; if (SPLIT) Bl += (size_t)bz * bBatch; }
    if (cBatch) { C += (size_t)bz * cBatch; }

    extern __shared__ __align__(16) unsigned short sm[];
    unsigned short* sAh = sm;            // 4096 ushorts (8 KB)
    unsigned short* sBh = sm + 4096;
    unsigned short* sAl = sm + 8192;     // only touched when SPLIT
    unsigned short* sBl = sm + 12288;

    const int t = threadIdx.x;
    const int wave = t >> 6, lane = t & 63;
    const int wr = wave >> 1, wc = wave & 1;
    const int mrow = lane & 15, kg = lane >> 4;

    int kEnd = K;
    if (CK) kEnd = min(K, row0 + 128);

    f32x4 acc[4][4] = {};

    const int c0 = wave * 2, c1 = wave * 2 + 1;
    size_t aOff0, aOff1;
    if (PACKA) {
        const int rblk = row0 >> 7;
        const size_t baseA = (((size_t)bz * 136) + (size_t)((rblk * (rblk + 1)) >> 1)) << 14;
        aOff0 = baseA + (size_t)(c0 * 16 + mrow) * 128 + kg * 8;
        aOff1 = baseA + (size_t)(c1 * 16 + mrow) * 128 + kg * 8;
    } else {
        aOff0 = (size_t)(row0 + c0 * 16 + mrow) * ldA + kg * 8;
        aOff1 = (size_t)(row0 + c1 * 16 + mrow) * ldA + kg * 8;
    }
    const size_t bOff0 = (size_t)(col0 + c0 * 16 + mrow) * ldB + kg * 8;
    const size_t bOff1 = (size_t)(col0 + c1 * 16 + mrow) * ldB + kg * 8;

    for (int k0 = 0; k0 < kEnd; k0 += 32) {
        // packed-A: block j = k0>>7 strides 16384, within-block col k0&127
        const size_t aK = PACKA ? ((((size_t)(k0 >> 7)) << 14) | (size_t)(k0 & 127))
                                : (size_t)k0;
        GLDS(Ah + aOff0 + aK, sAh + c0 * 512);
        GLDS(Ah + aOff1 + aK, sAh + c1 * 512);
        GLDS(Bh + bOff0 + k0, sBh + c0 * 512);
        GLDS(Bh + bOff1 + k0, sBh + c1 * 512);
        if (SPLIT) {
            GLDS(Al + aOff0 + aK, sAl + c0 * 512);
            GLDS(Al + aOff1 + aK, sAl + c1 * 512);
            GLDS(Bl + bOff0 + k0, sBl + c0 * 512);
            GLDS(Bl + bOff1 + k0, sBl + c1 * 512);
        }
        __syncthreads();   // compiler drains vmcnt before barrier

        bf16x8 afh[4], bfh[4], afl[4], bfl[4];
        #pragma unroll
        for (int i = 0; i < 4; ++i) {
            afh[i] = *(const bf16x8*)(sAh + (wr * 4 + i) * 512 + lane * 8);
            bfh[i] = *(const bf16x8*)(sBh + (wc * 4 + i) * 512 + lane * 8);
            if (SPLIT) {
                afl[i] = *(const bf16x8*)(sAl + (wr * 4 + i) * 512 + lane * 8);
                bfl[i] = *(const bf16x8*)(sBl + (wc * 4 + i) * 512 + lane * 8);
            }
        }
        #pragma unroll
        for (int i = 0; i < 4; ++i)
            #pragma unroll
            for (int j = 0; j < 4; ++j) {
                acc[i][j] = __builtin_amdgcn_mfma_f32_16x16x32_bf16(afh[i], bfh[j], acc[i][j], 0, 0, 0);
                if (SPLIT) {
                    acc[i][j] = __builtin_amdgcn_mfma_f32_16x16x32_bf16(afh[i], bfl[j], acc[i][j], 0, 0, 0);
                    acc[i][j] = __builtin_amdgcn_mfma_f32_16x16x32_bf16(afl[i], bfh[j], acc[i][j], 0, 0, 0);
                }
            }
        __syncthreads();
    }

    // epilogue: C/D layout col=lane&15, row=(lane>>4)*4+reg (m89-verified)
    float* Cout = C;
    size_t cbase = 0;
    if (PACKC) {
        const int rblk = row0 >> 7, cblk = col0 >> 7;
        Cout = (bz == 7) ? C7 : C + (size_t)bz * PACK_BATCH;   // hybrid: batch 7 in ws
        cbase = ((size_t)((rblk * (rblk + 1)) >> 1) + (size_t)cblk) << 14;
    }
    const int rb = (lane >> 4) * 4;
    const int cl = lane & 15;
    #pragma unroll
    for (int j = 0; j < 4; ++j) {
        const int col = col0 + wc * 64 + j * 16 + cl;
        float bv = BIAS ? bias[col] : 0.f;
        #pragma unroll
        for (int i = 0; i < 4; ++i) {
            const int rw = row0 + wr * 64 + i * 16 + rb;
            #pragma unroll
            for (int r = 0; r < 4; ++r) {
                const int row = rw + r;
                float v = acc[i][j][r];
                if (BIAS) v += bv;
                if (CMASK && col > row) v = -__builtin_huge_valf();
                const size_t off = PACKC
                    ? (cbase + (size_t)(row - row0) * 128 + (size_t)(col - col0))
                    : ((size_t)row * ldC + col);
                if (OUTF) Cout[off] = v;
                if (OUTH) {
                    unsigned short hh = f2bf(v);
                    Ch[off] = hh;
                    if (OUTL) Cl[off] = f2bf(v - bf2f(hh));
                }
            }
        }
    }
}

// ---------------- softmax: packed fp32 scores -> packed bf16 probabilities ----
// grid (S, Bn). Row q of batch b spans blocks j=0..(q>>7) of the packed
// triangular layout. Masked (-inf) diagonal-block entries -> exp 0, which PV's
// CK clip reads, so zeros there are required and provided.
__global__ __launch_bounds__(256)
void softmax_p_packed(const float* __restrict__ SF, const float* __restrict__ S7,
                      unsigned short* __restrict__ P)
{
    const int q = blockIdx.x, b = blockIdx.y;
    const int rblk = q >> 7, tri = (rblk * (rblk + 1)) >> 1;
    const size_t rowoff = ((size_t)tri << 14) + (size_t)(q & 127) * 128;
    const float* rowb = ((b == 7) ? S7 : SF + (size_t)b * PACK_BATCH) + rowoff;
    unsigned short* prow = P + (size_t)b * PACK_BATCH + rowoff;
    const int kend = rblk * 128 + 128;
    const int t = threadIdx.x;
    __shared__ float red[4];

    float m = -__builtin_huge_valf();
    for (int k = t; k < kend; k += 256)
        m = fmaxf(m, rowb[(((size_t)(k >> 7)) << 14) + (k & 127)]);
    #pragma unroll
    for (int off = 32; off; off >>= 1) m = fmaxf(m, __shfl_down(m, off, 64));
    if ((t & 63) == 0) red[t >> 6] = m;
    __syncthreads();
    m = fmaxf(fmaxf(red[0], red[1]), fmaxf(red[2], red[3]));
    __syncthreads();

    float e[8];
    float s = 0.f;
    int i = 0;
    for (int k = t; k < kend; k += 256, ++i) {
        float v = __expf(rowb[(((size_t)(k >> 7)) << 14) + (k & 127)] - m);
        e[i] = v;
        s += v;
    }
    #pragma unroll
    for (int off = 32; off; off >>= 1) s += __shfl_down(s, off, 64);
    if ((t & 63) == 0) red[t >> 6] = s;
    __syncthreads();
    s = red[0] + red[1] + red[2] + red[3];
    const float inv = 1.0f / s;
    i = 0;
    for (int k = t; k < kend; k += 256, ++i)
        prow[(((size_t)(k >> 7)) << 14) + (k & 127)] = f2bf(e[i] * inv);
}

// ---------------- fp32 fallback (round-1 kernels), used only if ws too small ----
#define TILE 64
#define KT 16
#define LDP (TILE + 4)
template<bool BT, bool BIAS, bool CMASK, bool CK>
__global__ __launch_bounds__(256)
void gemm_f32(const float* __restrict__ A, const float* __restrict__ B,
              const float* __restrict__ bias, float* __restrict__ C,
              int M, int N, int K, size_t sA, size_t sB, size_t sC)
{
    const int bm = blockIdx.y, bn = blockIdx.x;
    const int row0 = bm * TILE, col0 = bn * TILE;
    if (CMASK && col0 > row0 + (TILE - 1)) return;
    A += (size_t)blockIdx.z * sA; B += (size_t)blockIdx.z * sB; C += (size_t)blockIdx.z * sC;
    __shared__ float As[KT][LDP];
    __shared__ float Bs[KT][LDP];
    const int t = threadIdx.x;
    const int tx = t & 15, ty = t >> 4;
    const int lm = t >> 2, lk = (t & 3) << 2;
    int kEnd = K;
    if (CK) kEnd = min(K, row0 + TILE);
    float acc[4][4] = {};
    for (int k0 = 0; k0 < kEnd; k0 += KT) {
        {
            float4 a = *(const float4*)(A + (size_t)(row0 + lm) * K + (k0 + lk));
            As[lk + 0][lm] = a.x; As[lk + 1][lm] = a.y; As[lk + 2][lm] = a.z; As[lk + 3][lm] = a.w;
        }
        if (BT) {
            float4 b = *(const float4*)(B + (size_t)(col0 + lm) * K + (k0 + lk));
            Bs[lk + 0][lm] = b.x; Bs[lk + 1][lm] = b.y; Bs[lk + 2][lm] = b.z; Bs[lk + 3][lm] = b.w;
        } else {
            const int bk = t >> 4, bn4 = (t & 15) << 2;
            *(float4*)&Bs[bk][bn4] = *(const float4*)(B + (size_t)(k0 + bk) * N + (col0 + bn4));
        }
        __syncthreads();
        #pragma unroll
        for (int kk = 0; kk < KT; ++kk) {
            float av[4], bv[4];
            *(float4*)av = *(const float4*)&As[kk][ty << 2];
            *(float4*)bv = *(const float4*)&Bs[kk][tx << 2];
            #pragma unroll
            for (int i = 0; i < 4; ++i)
                #pragma unroll
                for (int j = 0; j < 4; ++j) acc[i][j] = fmaf(av[i], bv[j], acc[i][j]);
        }
        __syncthreads();
    }
    #pragma unroll
    for (int i = 0; i < 4; ++i) {
        const int r = row0 + (ty << 2) + i;
        float4 o; float* po = &o.x;
        #pragma unroll
        for (int j = 0; j < 4; ++j) {
            const int c = col0 + (tx << 2) + j;
            float v = acc[i][j];
            if (BIAS) v += bias[c];
            if (CMASK && c > r) v = -__builtin_huge_valf();
            po[j] = v;
        }
        *(float4*)(C + (size_t)r * N + col0 + (tx << 2)) = o;
    }
}
__global__ __launch_bounds__(256)
void softmax_causal(float* __restrict__ Sc, size_t batchStride, int ncols)
{
    const int q = blockIdx.x;
    float* row = Sc + (size_t)blockIdx.y * batchStride + (size_t)q * ncols;
    const int kend = (q & ~63) + 64;
    const int t = threadIdx.x;
    __shared__ float red[4];
    float m = -__builtin_huge_valf();
    for (int k = t; k < kend; k += 256) m = fmaxf(m, row[k]);
    #pragma unroll
    for (int off = 32; off; off >>= 1) m = fmaxf(m, __shfl_down(m, off, 64));
    if ((t & 63) == 0) red[t >> 6] = m;
    __syncthreads();
    m = fmaxf(fmaxf(red[0], red[1]), fmaxf(red[2], red[3]));
    __syncthreads();
    float e[8]; float s = 0.f; int i = 0;
    for (int k = t; k < kend; k += 256, ++i) { float v = __expf(row[k] - m); e[i] = v; s += v; }
    #pragma unroll
    for (int off = 32; off; off >>= 1) s += __shfl_down(s, off, 64);
    if ((t & 63) == 0) red[t >> 6] = s;
    __syncthreads();
    s = red[0] + red[1] + red[2] + red[3];
    const float inv = 1.0f / s;
    i = 0;
    for (int k = t; k < kend; k += 256, ++i) row[k] = e[i] * inv;
}

// ---------------- launch ----------------

extern "C" void kernel_launch(void* const* d_in, const int* in_sizes, int n_in,
                              void* d_out, int out_size, void* d_ws, size_t ws_size,
                              hipStream_t stream)
{
    const float* x_batch = (const float*)d_in[0];
    const float* lin_w   = (const float*)d_in[1];
    const float* lin_b   = (const float*)d_in[2];
    const float* W_q     = (const float*)d_in[3];
    const float* W_k     = (const float*)d_in[4];
    const float* W_v     = (const float*)d_in[5];

    constexpr int Bn = 8, S = 2048, D = 1024;
    constexpr size_t MS = (size_t)Bn * S;          // 16384
    constexpr size_t NE = MS * (size_t)D;          // 16,777,216
    constexpr size_t SB = (size_t)S * D;           // per-batch QKV stride

    float* out = (float*)d_out;
    float* Fo = out;
    float* Kc = out + NE;
    float* Vc = out + 2 * NE;

    // ws layout (bytes): Qh|Ql|Kh|Kl|X  (X = weights 14 MiB, later S batch-7)
    const size_t needFast = NE * 2 * 2ull      // Q pair (64 MiB)
                          + NE * 2 * 2ull      // K pair (64 MiB)
                          + 14680064ull;       // X = weights (S7 8.9 MB fits inside)

    if (ws_size >= needFast) {
        unsigned short* Qh  = (unsigned short*)d_ws;
        unsigned short* Ql  = Qh + NE;
        unsigned short* Kh  = Ql + NE;
        unsigned short* Kl  = Kh + NE;
        unsigned short* X   = Kl + NE;         // reused region
        unsigned short* lwh = X,            *lwl = X + 1048576;
        unsigned short* wqh = X + 2097152,  *wql = X + 3145728;
        unsigned short* wkh = X + 4194304,  *wkl = X + 5242880;
        unsigned short* wvh = X + 6291456;
        float*          S7f = (float*)X;                 // batch-7 packed S (8.9 MB)
        float*          SF  = Fo;                        // batches 0-6 packed S (62.4 MB)
        unsigned short* Ph  = Qh;                        // packed P overwrites dead Q pair
        unsigned short* VhT = Kh;                        // V^T overwrites dead K pair

        // staging in d_out dead regions
        unsigned short* xbh = (unsigned short*)Kc;   // K region dead until K GEMM
        unsigned short* xbl = xbh + NE;
        unsigned short* xh  = (unsigned short*)Fo;   // F region dead until S/PV
        unsigned short* xl  = xh + NE;

        const dim3 blk(256);

        // 1. conversions
        cvt_split<<<4096, blk, 0, stream>>>(x_batch, xbh, xbl, NE / 4);
        cvt_split<<<512,  blk, 0, stream>>>(lin_w, lwh, lwl, (size_t)D * D / 4);
        cvt_split_T<true ><<<dim3(16, 16, 1), blk, 0, stream>>>(W_q, wqh, wql, D, D, 0, 0);
        cvt_split_T<true ><<<dim3(16, 16, 1), blk, 0, stream>>>(W_k, wkh, wkl, D, D, 0, 0);
        cvt_split_T<false><<<dim3(16, 16, 1), blk, 0, stream>>>(W_v, wvh, nullptr, D, D, 0, 0);

        const dim3 gBig(D / 128, MS / 128);  // 8 x 128

        // 2. x = xb @ lin_w^T + b   (SPLIT, BIAS, out pair)
        gemm_bf16<true, true, false, false, false, true, true, false, false>
            <<<gBig, blk, 32768, stream>>>(xbh, xbl, lwh, lwl, lin_b,
                                           nullptr, nullptr, xh, xl, D, D, D, D, 0, 0, 0);
        // 3. Q = x @ W_q  (SPLIT, out pair)
        gemm_bf16<true, false, false, false, false, true, true, false, false>
            <<<gBig, blk, 32768, stream>>>(xh, xl, wqh, wql, nullptr,
                                           nullptr, nullptr, Qh, Ql, D, D, D, D, 0, 0, 0);
        // 4. K = x @ W_k  (SPLIT, out fp32 cache + pair)
        gemm_bf16<true, false, false, false, true, true, true, false, false>
            <<<gBig, blk, 32768, stream>>>(xh, xl, wkh, wkl, nullptr,
                                           Kc, nullptr, Kh, Kl, D, D, D, D, 0, 0, 0);
        // 5. V = x_h @ W_v_h  (single pass, fp32 cache)
        gemm_bf16<false, false, false, false, true, false, false, false, false>
            <<<gBig, blk, 16384, stream>>>(xh, nullptr, wvh, nullptr, nullptr,
                                           Vc, nullptr, nullptr, nullptr, D, D, D, D, 0, 0, 0);

        // 6. S = Q K^T causal, ALL batches, packed triangular (x pair now dead)
        gemm_bf16<true, false, true, false, true, false, false, true, false>
            <<<dim3(S / 128, S / 128, Bn), blk, 32768, stream>>>(
                Qh, Ql, Kh, Kl, nullptr,
                SF, S7f, nullptr, nullptr, D, D, D, 128, SB, SB, 0);

        // 7. P = softmax(S) -> packed bf16 into dead Q-pair region
        softmax_p_packed<<<dim3(S, Bn), blk, 0, stream>>>(SF, S7f, Ph);

        // 8. V_hT[b][h][s] = bf16(V[b][s][h]) into dead K-pair region
        cvt_split_T<false><<<dim3(D / 64, S / 64, Bn), blk, 0, stream>>>(
            Vc, VhT, nullptr, S, D, SB, SB);

        // 9. F = P @ V, ALL batches (packed A; S in F region is dead now)
        gemm_bf16<false, false, false, true, true, false, false, false, true>
            <<<dim3(D / 128, S / 128, Bn), blk, 16384, stream>>>(
                Ph, nullptr, VhT, nullptr, nullptr,
                Fo, nullptr, nullptr, nullptr, S, 128, S, D, 0, SB, SB);
    } else {
        // fp32 fallback (round-1 structure)
        float* x  = Fo;
        float* Q  = (float*)d_ws;
        float* Sc = Q + NE;
        const dim3 blk(256);
        const dim3 gBig(D / TILE, MS / TILE, 1);
        gemm_f32<true, true, false, false><<<gBig, blk, 0, stream>>>(
            x_batch, lin_w, lin_b, x, (int)MS, D, D, 0, 0, 0);
        gemm_f32<false, false, false, false><<<gBig, blk, 0, stream>>>(
            x, W_q, nullptr, Q, (int)MS, D, D, 0, 0, 0);
        gemm_f32<false, false, false, false><<<gBig, blk, 0, stream>>>(
            x, W_k, nullptr, Kc, (int)MS, D, D, 0, 0, 0);
        gemm_f32<false, false, false, false><<<gBig, blk, 0, stream>>>(
            x, W_v, nullptr, Vc, (int)MS, D, D, 0, 0, 0);
        for (int b = 0; b < Bn; ++b) {
            const float* Qb = Q  + (size_t)b * SB;
            const float* Kb = Kc + (size_t)b * SB;
            const float* Vb = Vc + (size_t)b * SB;
            float*       Fb = Fo + (size_t)b * SB;
            gemm_f32<true, false, true, false><<<dim3(S / TILE, S / TILE, 1), blk, 0, stream>>>(
                Qb, Kb, nullptr, Sc, S, S, D, 0, 0, 0);
            softmax_causal<<<dim3(S, 1, 1), blk, 0, stream>>>(Sc, 0, S);
            gemm_f32<false, false, false, true><<<dim3(D / TILE, S / TILE, 1), blk, 0, stream>>>(
                Sc, Vb, nullptr, Fb, S, D, S, 0, 0, 0);
        }
    }
}

// Round 2
// 1062.768 us; speedup vs baseline: 1.7934x; 1.1732x over previous
//
#include <hip/hip_runtime.h>
#include <cstdint>
#include <cstddef>
#include <cmath>

// B=8, S=2048, D=H=1024, fp32 in/out.
// Pipeline (all GEMMs on bf16 MFMA 16x16x32, fp32 accumulate):
//   split(x_batch), split(lin_w), splitT(W_q), splitT(W_k), splitT_h(W_v)
//   x   = xb @ lin_w^T + b      [SPLIT 3-pass, 256^2 pipelined, out pair -> F region]
//   Q,K = x @ W                 [SPLIT, 256^2 pipelined, out pairs (+K fp32 cache)]
//   V   = x_h @ W_v_h           [256^2 pipelined, fp32 cache]
//   S_b = Q_b K_b^T (causal)    [SPLIT, 256^2 pipelined, compact triangle grid,
//                                batch-per-XCD, packed-triangular fp32 out]
//   P_b = softmax(S_b) -> bf16  [packed, one dispatch]
//   V^T transpose               [into dead K-pair region]
//   F_b = P_b @ V_b             [128^2 kernel, packed-A]
//
// 256^2 GEMM: 8 waves (2Mx4N), BK=32, double-buffered fragment-contiguous LDS
// (chunk c = rows [16c,16c+16) x 32k in MFMA lane order -> global_load_lds
// writes it directly, ds_read_b128 at lane*16 conflict-free). Prefetch next
// K-step before compute; ONE __syncthreads per step (its implicit vmcnt drain
// lands after the 96-MFMA compute phase -> HBM latency hidden). setprio(1)
// around MFMA. SPLIT LDS = 4 planes x 16KB x 2buf = 128 KB -> 1 block/CU.
//
// Causal-packed S: 136 lower-triangle 128x128 blocks/batch. Batches 0-6 in F
// region (dead), batch 7 in ws weights region (dead after V GEMM). P bf16
// overwrites dead Q pair; VhT overwrites dead K pair.

typedef short bf16x8 __attribute__((ext_vector_type(8)));
typedef float f32x4 __attribute__((ext_vector_type(4)));

__device__ __forceinline__ unsigned short f2bf(float f) {
    unsigned u = __float_as_uint(f);
    return (unsigned short)((u + 0x7fffu + ((u >> 16) & 1u)) >> 16);
}
__device__ __forceinline__ float bf2f(unsigned short h) {
    return __uint_as_float(((unsigned)h) << 16);
}

#define GLDS(gp, lp)                                                                \
    __builtin_amdgcn_global_load_lds((const __attribute__((address_space(1))) void*)(gp), \
                                     (__attribute__((address_space(3))) void*)(lp), 16, 0, 0)

// packed-S constants: 136 blocks/batch, 16384 elems/block
#define PACK_BATCH ((size_t)136 * 16384)

// ---------------- conversion kernels ----------------

__global__ __launch_bounds__(256)
void cvt_split(const float* __restrict__ in, unsigned short* __restrict__ h,
               unsigned short* __restrict__ l, size_t n4)
{
    size_t i = (size_t)blockIdx.x * blockDim.x + threadIdx.x;
    size_t stride = (size_t)gridDim.x * blockDim.x;
    for (; i < n4; i += stride) {
        float4 v = ((const float4*)in)[i];
        unsigned short h0 = f2bf(v.x), h1 = f2bf(v.y), h2 = f2bf(v.z), h3 = f2bf(v.w);
        uint2 hp, lp;
        hp.x = (unsigned)h0 | ((unsigned)h1 << 16);
        hp.y = (unsigned)h2 | ((unsigned)h3 << 16);
        lp.x = (unsigned)f2bf(v.x - bf2f(h0)) | ((unsigned)f2bf(v.y - bf2f(h1)) << 16);
        lp.y = (unsigned)f2bf(v.z - bf2f(h2)) | ((unsigned)f2bf(v.w - bf2f(h3)) << 16);
        ((uint2*)h)[i] = hp;
        ((uint2*)l)[i] = lp;
    }
}

// out[c][r] = in[r][c], fp32 -> bf16 hi (+lo). Coalesced both sides via LDS tile.
template<bool PAIR>
__global__ __launch_bounds__(256)
void cvt_split_T(const float* __restrict__ in, unsigned short* __restrict__ hT,
                 unsigned short* __restrict__ lT, int R, int C,
                 size_t inBatch, size_t outBatch)
{
    __shared__ float tile[64][65];
    in += (size_t)blockIdx.z * inBatch;
    hT += (size_t)blockIdx.z * outBatch;
    const int c0 = blockIdx.x * 64, r0 = blockIdx.y * 64;
    const int tx = threadIdx.x & 63, ty = threadIdx.x >> 6;
    for (int i = ty; i < 64; i += 4)
        tile[i][tx] = in[(size_t)(r0 + i) * C + c0 + tx];
    __syncthreads();
    for (int i = ty; i < 64; i += 4) {
        float v = tile[tx][i];
        unsigned short hh = f2bf(v);
        size_t off = (size_t)(c0 + i) * R + r0 + tx;
        hT[off] = hh;
        if (PAIR) (lT + (size_t)blockIdx.z * outBatch)[off] = f2bf(v - bf2f(hh));
    }
}

// ---------------- 256x256 pipelined MFMA GEMM, BT layout ----------------
// C[M,N] = (Ah+Al)[M,K] @ (Bh+Bl)[N,K]^T.  8 waves as 2Mx4N (wave tile 128x64).
// Dense mode: 1D grid, chunked-bijective XCD swizzle (4 col-blocks of a row
// panel land on one XCD -> A panel fetched once per XCD).
// QKT mode: compact triangle grid (36 supertiles x 8 batches), batch = bid%8
// (aligns batch to XCD), causal mask + packed-triangular store (skip the
// upper-right 128-quadrant of diagonal supertiles; it has no packed slot).

template<bool SPLIT, bool BIAS, bool QKT, bool OUTF, bool OUTH, bool OUTL>
__global__ __launch_bounds__(512, 2)
void gemm256(const unsigned short* __restrict__ Ah, const unsigned short* __restrict__ Al,
             const unsigned short* __restrict__ Bh, const unsigned short* __restrict__ Bl,
             const float* __restrict__ bias,
             float* __restrict__ C, float* __restrict__ C7,
             unsigned short* __restrict__ Ch, unsigned short* __restrict__ Cl,
             int K, int ldA, int ldB, int ldC, int nbx,
             size_t aBatch, size_t bBatch)
{
    int row0, col0, batch = 0;
    if (QKT) {
        const int bid = blockIdx.x;
        batch = bid & 7;                 // batch <-> XCD alignment
        const int ti = bid >> 3;         // triangle index 0..35
        int r = (int)((sqrtf(8.f * (float)ti + 1.f) - 1.f) * 0.5f);
        while (((r + 1) * (r + 2)) / 2 <= ti) ++r;
        while ((r * (r + 1)) / 2 > ti) --r;
        const int c = ti - (r * (r + 1)) / 2;
        row0 = r * 256; col0 = c * 256;
        Ah += (size_t)batch * aBatch; Bh += (size_t)batch * bBatch;
        if (SPLIT) { Al += (size_t)batch * aBatch; Bl += (size_t)batch * bBatch; }
    } else {
        const int bid = blockIdx.x;
        const int chunk = gridDim.x >> 3;              // gridDim.x % 8 == 0
        const int lb = (bid & 7) * chunk + (bid >> 3); // bijective XCD chunking
        row0 = (lb / nbx) * 256; col0 = (lb % nbx) * 256;
    }

    constexpr int PL = 8192;                      // plane length (ushorts) = 16 KB
    constexpr int BUF = SPLIT ? 32768 : 16384;    // buffer length (ushorts)
    __shared__ unsigned short sm[SPLIT ? 65536 : 32768];

    const int t = threadIdx.x, wave = t >> 6, lane = t & 63;
    const int wr = wave >> 2, wc = wave & 3;      // 2 x 4 wave grid
    const int mrow = lane & 15, kg = lane >> 4;
    const int c0 = wave * 2, c1 = wave * 2 + 1;   // staging chunks of this wave

    const size_t aOff0 = (size_t)(row0 + c0 * 16 + mrow) * ldA + kg * 8;
    const size_t aOff1 = (size_t)(row0 + c1 * 16 + mrow) * ldA + kg * 8;
    const size_t bOff0 = (size_t)(col0 + c0 * 16 + mrow) * ldB + kg * 8;
    const size_t bOff1 = (size_t)(col0 + c1 * 16 + mrow) * ldB + kg * 8;

    f32x4 acc[8][4] = {};
    const int nt = K / 32;

#define STAGE256(step, bb)                                                   \
    do {                                                                     \
        unsigned short* db = sm + (bb);                                      \
        const size_t kof = (size_t)(step) * 32;                              \
        GLDS(Ah + aOff0 + kof, db + c0 * 512);                               \
        GLDS(Ah + aOff1 + kof, db + c1 * 512);                               \
        GLDS(Bh + bOff0 + kof, db + (SPLIT ? 2 * PL : PL) + c0 * 512);       \
        GLDS(Bh + bOff1 + kof, db + (SPLIT ? 2 * PL : PL) + c1 * 512);       \
        if (SPLIT) {                                                         \
            GLDS(Al + aOff0 + kof, db + PL + c0 * 512);                      \
            GLDS(Al + aOff1 + kof, db + PL + c1 * 512);                      \
            GLDS(Bl + bOff0 + kof, db + 3 * PL + c0 * 512);                  \
            GLDS(Bl + bOff1 + kof, db + 3 * PL + c1 * 512);                  \
        }                                                                    \
    } while (0)

    STAGE256(0, 0);
    __syncthreads();   // drains vmcnt: buf0 staged

    for (int ts = 0; ts < nt; ++ts) {
        unsigned short* sb = sm + (ts & 1) * BUF;
        if (ts + 1 < nt) STAGE256(ts + 1, ((ts + 1) & 1) * BUF);  // prefetch early
        bf16x8 bh[4], bl[4];
        #pragma unroll
        for (int j = 0; j < 4; ++j) {
            bh[j] = *(const bf16x8*)(sb + (SPLIT ? 2 * PL : PL) + (wc * 4 + j) * 512 + lane * 8);
            if (SPLIT) bl[j] = *(const bf16x8*)(sb + 3 * PL + (wc * 4 + j) * 512 + lane * 8);
        }
        #pragma unroll
        for (int i = 0; i < 8; ++i) {
            bf16x8 ah = *(const bf16x8*)(sb + (wr * 8 + i) * 512 + lane * 8);
            bf16x8 al;
            if (SPLIT) al = *(const bf16x8*)(sb + PL + (wr * 8 + i) * 512 + lane * 8);
            __builtin_amdgcn_s_setprio(1);
            #pragma unroll
            for (int j = 0; j < 4; ++j) {
                acc[i][j] = __builtin_amdgcn_mfma_f32_16x16x32_bf16(ah, bh[j], acc[i][j], 0, 0, 0);
                if (SPLIT) {
                    acc[i][j] = __builtin_amdgcn_mfma_f32_16x16x32_bf16(ah, bl[j], acc[i][j], 0, 0, 0);
                    acc[i][j] = __builtin_amdgcn_mfma_f32_16x16x32_bf16(al, bh[j], acc[i][j], 0, 0, 0);
                }
            }
            __builtin_amdgcn_s_setprio(0);
        }
        __syncthreads();  // implicit vmcnt(0) drain covers the prefetch
    }
#undef STAGE256

    // epilogue: C/D layout col=lane&15, row=(lane>>4)*4+reg (m89-verified)
    float* Cout = C;
    if (QKT) Cout = (batch == 7) ? C7 : C + (size_t)batch * PACK_BATCH;
    const int rb = (lane >> 4) * 4, cl = lane & 15;
    #pragma unroll
    for (int j = 0; j < 4; ++j) {
        const int col = col0 + wc * 64 + j * 16 + cl;
        const float bv = BIAS ? bias[col] : 0.f;
        #pragma unroll
        for (int i = 0; i < 8; ++i) {
            const int rw = row0 + wr * 128 + i * 16 + rb;
            #pragma unroll
            for (int r = 0; r < 4; ++r) {
                const int row = rw + r;
                float v = acc[i][j][r];
                if (BIAS) v += bv;
                if (QKT) {
                    if (col > row) v = -__builtin_huge_valf();
                    const int rblk = row >> 7, cblk = col >> 7;
                    if (rblk >= cblk) {
                        const size_t off = ((size_t)(((rblk * (rblk + 1)) >> 1) + cblk) << 14)
                                         + ((size_t)(row & 127) << 7) + (size_t)(col & 127);
                        Cout[off] = v;
                    }
                } else {
                    const size_t off = (size_t)row * ldC + col;
                    if (OUTF) Cout[off] = v;
                    if (OUTH) {
                        unsigned short hh = f2bf(v);
                        Ch[off] = hh;
                        if (OUTL) Cl[off] = f2bf(v - bf2f(hh));
                    }
                }
            }
        }
    }
}

// ---------------- 128x128 MFMA GEMM (kept for PV: packed-A, CK clip) --------

template<bool SPLIT, bool BIAS, bool CMASK, bool CK, bool OUTF, bool OUTH, bool OUTL,
         bool PACKC, bool PACKA>
__global__ __launch_bounds__(256)
void gemm_bf16(const unsigned short* __restrict__ Ah, const unsigned short* __restrict__ Al,
               const unsigned short* __restrict__ Bh, const unsigned short* __restrict__ Bl,
               const float* __restrict__ bias,
               float* __restrict__ C, float* __restrict__ C7,
               unsigned short* __restrict__ Ch, unsigned short* __restrict__ Cl,
               int K, int ldA, int ldB, int ldC,
               size_t aBatch, size_t bBatch, size_t cBatch)
{
    const int row0 = blockIdx.y * 128, col0 = blockIdx.x * 128;
    if (CMASK && col0 > row0 + 127) return;

    const int bz = blockIdx.z;
    if (aBatch) { Ah += (size_t)bz * aBatch; if (SPLIT) Al += (size_t)bz * aBatch; }
    if (bBatch) { Bh += (size_t)bz * bBatch; if (SPLIT) Bl += (size_t)bz * bBatch; }
    if (cBatch) { C += (size_t)bz * cBatch; }

    extern __shared__ __align__(16) unsigned short smd[];
    unsigned short* sAh = smd;
    unsigned short* sBh = smd + 4096;
    unsigned short* sAl = smd + 8192;
    unsigned short* sBl = smd + 12288;

    const int t = threadIdx.x;
    const int wave = t >> 6, lane = t & 63;
    const int wr = wave >> 1, wc = wave & 1;
    const int mrow = lane & 15, kg = lane >> 4;

    int kEnd = K;
    if (CK) kEnd = min(K, row0 + 128);

    f32x4 acc[4][4] = {};

    const int c0 = wave * 2, c1 = wave * 2 + 1;
    size_t aOff0, aOff1;
    if (PACKA) {
        const int rblk = row0 >> 7;
        const size_t baseA = (((size_t)bz * 136) + (size_t)((rblk * (rblk + 1)) >> 1)) << 14;
        aOff0 = baseA + (size_t)(c0 * 16 + mrow) * 128 + kg * 8;
        aOff1 = baseA + (size_t)(c1 * 16 + mrow) * 128 + kg * 8;
    } else {
        aOff0 = (size_t)(row0 + c0 * 16 + mrow) * ldA + kg * 8;
        aOff1 = (size_t)(row0 + c1 * 16 + mrow) * ldA + kg * 8;
    }
    const size_t bOff0 = (size_t)(col0 + c0 * 16 + mrow) * ldB + kg * 8;
    const size_t bOff1 = (size_t)(col0 + c1 * 16 + mrow) * ldB + kg * 8;

    for (int k0 = 0; k0 < kEnd; k0 += 32) {
        const size_t aK = PACKA ? ((((size_t)(k0 >> 7)) << 14) | (size_t)(k0 & 127))
                                : (size_t)k0;
        GLDS(Ah + aOff0 + aK, sAh + c0 * 512);
        GLDS(Ah + aOff1 + aK, sAh + c1 * 512);
        GLDS(Bh + bOff0 + k0, sBh + c0 * 512);
        GLDS(Bh + bOff1 + k0, sBh + c1 * 512);
        if (SPLIT) {
            GLDS(Al + aOff0 + aK, sAl + c0 * 512);
            GLDS(Al + aOff1 + aK, sAl + c1 * 512);
            GLDS(Bl + bOff0 + k0, sBl + c0 * 512);
            GLDS(Bl + bOff1 + k0, sBl + c1 * 512);
        }
        __syncthreads();

        bf16x8 afh[4], bfh[4], afl[4], bfl[4];
        #pragma unroll
        for (int i = 0; i < 4; ++i) {
            afh[i] = *(const bf16x8*)(sAh + (wr * 4 + i) * 512 + lane * 8);
            bfh[i] = *(const bf16x8*)(sBh + (wc * 4 + i) * 512 + lane * 8);
            if (SPLIT) {
                afl[i] = *(const bf16x8*)(sAl + (wr * 4 + i) * 512 + lane * 8);
                bfl[i] = *(const bf16x8*)(sBl + (wc * 4 + i) * 512 + lane * 8);
            }
        }
        #pragma unroll
        for (int i = 0; i < 4; ++i)
            #pragma unroll
            for (int j = 0; j < 4; ++j) {
                acc[i][j] = __builtin_amdgcn_mfma_f32_16x16x32_bf16(afh[i], bfh[j], acc[i][j], 0, 0, 0);
                if (SPLIT) {
                    acc[i][j] = __builtin_amdgcn_mfma_f32_16x16x32_bf16(afh[i], bfl[j], acc[i][j], 0, 0, 0);
                    acc[i][j] = __builtin_amdgcn_mfma_f32_16x16x32_bf16(afl[i], bfh[j], acc[i][j], 0, 0, 0);
                }
            }
        __syncthreads();
    }

    float* Cout = C;
    size_t cbase = 0;
    if (PACKC) {
        const int rblk = row0 >> 7, cblk = col0 >> 7;
        Cout = (bz == 7) ? C7 : C + (size_t)bz * PACK_BATCH;
        cbase = ((size_t)((rblk * (rblk + 1)) >> 1) + (size_t)cblk) << 14;
    }
    const int rb = (lane >> 4) * 4;
    const int cl = lane & 15;
    #pragma unroll
    for (int j = 0; j < 4; ++j) {
        const int col = col0 + wc * 64 + j * 16 + cl;
        float bv = BIAS ? bias[col] : 0.f;
        #pragma unroll
        for (int i = 0; i < 4; ++i) {
            const int rw = row0 + wr * 64 + i * 16 + rb;
            #pragma unroll
            for (int r = 0; r < 4; ++r) {
                const int row = rw + r;
                float v = acc[i][j][r];
                if (BIAS) v += bv;
                if (CMASK && col > row) v = -__builtin_huge_valf();
                const size_t off = PACKC
                    ? (cbase + (size_t)(row - row0) * 128 + (size_t)(col - col0))
                    : ((size_t)row * ldC + col);
                if (OUTF) Cout[off] = v;
                if (OUTH) {
                    unsigned short hh = f2bf(v);
                    Ch[off] = hh;
                    if (OUTL) Cl[off] = f2bf(v - bf2f(hh));
                }
            }
        }
    }
}

// ---------------- softmax: packed fp32 scores -> packed bf16 probabilities ----
__global__ __launch_bounds__(256)
void softmax_p_packed(const float* __restrict__ SF, const float* __restrict__ S7,
                      unsigned short* __restrict__ P)
{
    const int q = blockIdx.x, b = blockIdx.y;
    const int rblk = q >> 7, tri = (rblk * (rblk + 1)) >> 1;
    const size_t rowoff = ((size_t)tri << 14) + (size_t)(q & 127) * 128;
    const float* rowb = ((b == 7) ? S7 : SF + (size_t)b * PACK_BATCH) + rowoff;
    unsigned short* prow = P + (size_t)b * PACK_BATCH + rowoff;
    const int kend = rblk * 128 + 128;
    const int t = threadIdx.x;
    __shared__ float red[4];

    float m = -__builtin_huge_valf();
    for (int k = t; k < kend; k += 256)
        m = fmaxf(m, rowb[(((size_t)(k >> 7)) << 14) + (k & 127)]);
    #pragma unroll
    for (int off = 32; off; off >>= 1) m = fmaxf(m, __shfl_down(m, off, 64));
    if ((t & 63) == 0) red[t >> 6] = m;
    __syncthreads();
    m = fmaxf(fmaxf(red[0], red[1]), fmaxf(red[2], red[3]));
    __syncthreads();

    float e[8];
    float s = 0.f;
    int i = 0;
    for (int k = t; k < kend; k += 256, ++i) {
        float v = __expf(rowb[(((size_t)(k >> 7)) << 14) + (k & 127)] - m);
        e[i] = v;
        s += v;
    }
    #pragma unroll
    for (int off = 32; off; off >>= 1) s += __shfl_down(s, off, 64);
    if ((t & 63) == 0) red[t >> 6] = s;
    __syncthreads();
    s = red[0] + red[1] + red[2] + red[3];
    const float inv = 1.0f / s;
    i = 0;
    for (int k = t; k < kend; k += 256, ++i)
        prow[(((size_t)(k >> 7)) << 14) + (k & 127)] = f2bf(e[i] * inv);
}

// ---------------- fp32 fallback (round-1 kernels), used only if ws too small ----
#define TILE 64
#define KT 16
#define LDP (TILE + 4)
template<bool BT, bool BIAS, bool CMASK, bool CK>
__global__ __launch_bounds__(256)
void gemm_f32(const float* __restrict__ A, const float* __restrict__ B,
              const float* __restrict__ bias, float* __restrict__ C,
              int M, int N, int K, size_t sA, size_t sB, size_t sC)
{
    const int bm = blockIdx.y, bn = blockIdx.x;
    const int row0 = bm * TILE, col0 = bn * TILE;
    if (CMASK && col0 > row0 + (TILE - 1)) return;
    A += (size_t)blockIdx.z * sA; B += (size_t)blockIdx.z * sB; C += (size_t)blockIdx.z * sC;
    __shared__ float As[KT][LDP];
    __shared__ float Bs[KT][LDP];
    const int t = threadIdx.x;
    const int tx = t & 15, ty = t >> 4;
    const int lm = t >> 2, lk = (t & 3) << 2;
    int kEnd = K;
    if (CK) kEnd = min(K, row0 + TILE);
    float acc[4][4] = {};
    for (int k0 = 0; k0 < kEnd; k0 += KT) {
        {
            float4 a = *(const float4*)(A + (size_t)(row0 + lm) * K + (k0 + lk));
            As[lk + 0][lm] = a.x; As[lk + 1][lm] = a.y; As[lk + 2][lm] = a.z; As[lk + 3][lm] = a.w;
        }
        if (BT) {
            float4 b = *(const float4*)(B + (size_t)(col0 + lm) * K + (k0 + lk));
            Bs[lk + 0][lm] = b.x; Bs[lk + 1][lm] = b.y; Bs[lk + 2][lm] = b.z; Bs[lk + 3][lm] = b.w;
        } else {
            const int bk = t >> 4, bn4 = (t & 15) << 2;
            *(float4*)&Bs[bk][bn4] = *(const float4*)(B + (size_t)(k0 + bk) * N + (col0 + bn4));
        }
        __syncthreads();
        #pragma unroll
        for (int kk = 0; kk < KT; ++kk) {
            float av[4], bv[4];
            *(float4*)av = *(const float4*)&As[kk][ty << 2];
            *(float4*)bv = *(const float4*)&Bs[kk][tx << 2];
            #pragma unroll
            for (int i = 0; i < 4; ++i)
                #pragma unroll
                for (int j = 0; j < 4; ++j) acc[i][j] = fmaf(av[i], bv[j], acc[i][j]);
        }
        __syncthreads();
    }
    #pragma unroll
    for (int i = 0; i < 4; ++i) {
        const int r = row0 + (ty << 2) + i;
        float4 o; float* po = &o.x;
        #pragma unroll
        for (int j = 0; j < 4; ++j) {
            const int c = col0 + (tx << 2) + j;
            float v = acc[i][j];
            if (BIAS) v += bias[c];
            if (CMASK && c > r) v = -__builtin_huge_valf();
            po[j] = v;
        }
        *(float4*)(C + (size_t)r * N + col0 + (tx << 2)) = o;
    }
}
__global__ __launch_bounds__(256)
void softmax_causal(float* __restrict__ Sc, size_t batchStride, int ncols)
{
    const int q = blockIdx.x;
    float* row = Sc + (size_t)blockIdx.y * batchStride + (size_t)q * ncols;
    const int kend = (q & ~63) + 64;
    const int t = threadIdx.x;
    __shared__ float red[4];
    float m = -__builtin_huge_valf();
    for (int k = t; k < kend; k += 256) m = fmaxf(m, row[k]);
    #pragma unroll
    for (int off = 32; off; off >>= 1) m = fmaxf(m, __shfl_down(m, off, 64));
    if ((t & 63) == 0) red[t >> 6] = m;
    __syncthreads();
    m = fmaxf(fmaxf(red[0], red[1]), fmaxf(red[2], red[3]));
    __syncthreads();
    float e[8]; float s = 0.f; int i = 0;
    for (int k = t; k < kend; k += 256, ++i) { float v = __expf(row[k] - m); e[i] = v; s += v; }
    #pragma unroll
    for (int off = 32; off; off >>= 1) s += __shfl_down(s, off, 64);
    if ((t & 63) == 0) red[t >> 6] = s;
    __syncthreads();
    s = red[0] + red[1] + red[2] + red[3];
    const float inv = 1.0f / s;
    i = 0;
    for (int k = t; k < kend; k += 256, ++i) row[k] = e[i] * inv;
}

// ---------------- launch ----------------

extern "C" void kernel_launch(void* const* d_in, const int* in_sizes, int n_in,
                              void* d_out, int out_size, void* d_ws, size_t ws_size,
                              hipStream_t stream)
{
    const float* x_batch = (const float*)d_in[0];
    const float* lin_w   = (const float*)d_in[1];
    const float* lin_b   = (const float*)d_in[2];
    const float* W_q     = (const float*)d_in[3];
    const float* W_k     = (const float*)d_in[4];
    const float* W_v     = (const float*)d_in[5];

    constexpr int Bn = 8, S = 2048, D = 1024;
    constexpr size_t MS = (size_t)Bn * S;          // 16384
    constexpr size_t NE = MS * (size_t)D;          // 16,777,216
    constexpr size_t SB = (size_t)S * D;           // per-batch QKV stride

    float* out = (float*)d_out;
    float* Fo = out;
    float* Kc = out + NE;
    float* Vc = out + 2 * NE;

    // ws layout (bytes): Qh|Ql|Kh|Kl|X  (X = weights 14 MiB, later S batch-7)
    const size_t needFast = NE * 2 * 2ull      // Q pair (64 MiB)
                          + NE * 2 * 2ull      // K pair (64 MiB)
                          + 14680064ull;       // X = weights (S7 8.9 MB fits inside)

    if (ws_size >= needFast) {
        unsigned short* Qh  = (unsigned short*)d_ws;
        unsigned short* Ql  = Qh + NE;
        unsigned short* Kh  = Ql + NE;
        unsigned short* Kl  = Kh + NE;
        unsigned short* X   = Kl + NE;         // reused region
        unsigned short* lwh = X,            *lwl = X + 1048576;
        unsigned short* wqh = X + 2097152,  *wql = X + 3145728;
        unsigned short* wkh = X + 4194304,  *wkl = X + 5242880;
        unsigned short* wvh = X + 6291456;
        float*          S7f = (float*)X;                 // batch-7 packed S (8.9 MB)
        float*          SF  = Fo;                        // batches 0-6 packed S (62.4 MB)
        unsigned short* Ph  = Qh;                        // packed P overwrites dead Q pair
        unsigned short* VhT = Kh;                        // V^T overwrites dead K pair

        // staging in d_out dead regions
        unsigned short* xbh = (unsigned short*)Kc;   // K region dead until K GEMM
        unsigned short* xbl = xbh + NE;
        unsigned short* xh  = (unsigned short*)Fo;   // F region dead until S/PV
        unsigned short* xl  = xh + NE;

        const dim3 blk(256);
        const dim3 blk512(512);

        // 1. conversions
        cvt_split<<<4096, blk, 0, stream>>>(x_batch, xbh, xbl, NE / 4);
        cvt_split<<<512,  blk, 0, stream>>>(lin_w, lwh, lwl, (size_t)D * D / 4);
        cvt_split_T<true ><<<dim3(16, 16, 1), blk, 0, stream>>>(W_q, wqh, wql, D, D, 0, 0);
        cvt_split_T<true ><<<dim3(16, 16, 1), blk, 0, stream>>>(W_k, wkh, wkl, D, D, 0, 0);
        cvt_split_T<false><<<dim3(16, 16, 1), blk, 0, stream>>>(W_v, wvh, nullptr, D, D, 0, 0);

        // 2. x = xb @ lin_w^T + b   (SPLIT, BIAS, out pair)  grid 64x4=256 blocks
        gemm256<true, true, false, false, true, true><<<dim3(256), blk512, 0, stream>>>(
            xbh, xbl, lwh, lwl, lin_b, nullptr, nullptr, xh, xl, D, D, D, D, 4, 0, 0);
        // 3. Q = x @ W_q  (SPLIT, out pair)
        gemm256<true, false, false, false, true, true><<<dim3(256), blk512, 0, stream>>>(
            xh, xl, wqh, wql, nullptr, nullptr, nullptr, Qh, Ql, D, D, D, D, 4, 0, 0);
        // 4. K = x @ W_k  (SPLIT, out fp32 cache + pair)
        gemm256<true, false, false, true, true, true><<<dim3(256), blk512, 0, stream>>>(
            xh, xl, wkh, wkl, nullptr, Kc, nullptr, Kh, Kl, D, D, D, D, 4, 0, 0);
        // 5. V = x_h @ W_v_h  (single pass, fp32 cache)
        gemm256<false, false, false, true, false, false><<<dim3(256), blk512, 0, stream>>>(
            xh, nullptr, wvh, nullptr, nullptr, Vc, nullptr, nullptr, nullptr,
            D, D, D, D, 4, 0, 0);

        // 6. S = Q K^T causal, ALL batches, compact triangle (36 x 8 = 288 blocks)
        gemm256<true, false, true, true, false, false><<<dim3(288), blk512, 0, stream>>>(
            Qh, Ql, Kh, Kl, nullptr, SF, S7f, nullptr, nullptr,
            D, D, D, 128, 1, SB, SB);

        // 7. P = softmax(S) -> packed bf16 into dead Q-pair region
        softmax_p_packed<<<dim3(S, Bn), blk, 0, stream>>>(SF, S7f, Ph);

        // 8. V_hT[b][h][s] = bf16(V[b][s][h]) into dead K-pair region
        cvt_split_T<false><<<dim3(D / 64, S / 64, Bn), blk, 0, stream>>>(
            Vc, VhT, nullptr, S, D, SB, SB);

        // 9. F = P @ V, ALL batches (packed A; S in F region is dead now)
        gemm_bf16<false, false, false, true, true, false, false, false, true>
            <<<dim3(D / 128, S / 128, Bn), blk, 16384, stream>>>(
                Ph, nullptr, VhT, nullptr, nullptr,
                Fo, nullptr, nullptr, nullptr, S, 128, S, D, 0, SB, SB);
    } else {
        // fp32 fallback (round-1 structure)
        float* x  = Fo;
        float* Q  = (float*)d_ws;
        float* Sc = Q + NE;
        const dim3 blk(256);
        const dim3 gBig(D / TILE, MS / TILE, 1);
        gemm_f32<true, true, false, false><<<gBig, blk, 0, stream>>>(
            x_batch, lin_w, lin_b, x, (int)MS, D, D, 0, 0, 0);
        gemm_f32<false, false, false, false><<<gBig, blk, 0, stream>>>(
            x, W_q, nullptr, Q, (int)MS, D, D, 0, 0, 0);
        gemm_f32<false, false, false, false><<<gBig, blk, 0, stream>>>(
            x, W_k, nullptr, Kc, (int)MS, D, D, 0, 0, 0);
        gemm_f32<false, false, false, false><<<gBig, blk, 0, stream>>>(
            x, W_v, nullptr, Vc, (int)MS, D, D, 0, 0, 0);
        for (int b = 0; b < Bn; ++b) {
            const float* Qb = Q  + (size_t)b * SB;
            const float* Kb = Kc + (size_t)b * SB;
            const float* Vb = Vc + (size_t)b * SB;
            float*       Fb = Fo + (size_t)b * SB;
            gemm_f32<true, false, true, false><<<dim3(S / TILE, S / TILE, 1), blk, 0, stream>>>(
                Qb, Kb, nullptr, Sc, S, S, D, 0, 0, 0);
            softmax_causal<<<dim3(S, 1, 1), blk, 0, stream>>>(Sc, 0, S);
            gemm_f32<false, false, false, true><<<dim3(D / TILE, S / TILE, 1), blk, 0, stream>>>(
                Sc, Vb, nullptr, Fb, S, D, S, 0, 0, 0);
        }
    }
}